// Round 1
// 182.055 us; speedup vs baseline: 1.0788x; 1.0788x over previous
//
#include <hip/hip_runtime.h>
#include <hip/hip_bf16.h>
#include <math.h>

#define Bn 16
#define Tn 512
#define HIDn 1024
#define NHn 8
#define NKVn 4
#define Dn 128

typedef __attribute__((ext_vector_type(8))) short short8;
typedef __attribute__((ext_vector_type(4))) float floatx4;

__device__ __forceinline__ short bf16r(float f) {
  __hip_bfloat16 h = __float2bfloat16(f);
  return *(short*)&h;
}
__device__ __forceinline__ float bf16f(short s) {
  __hip_bfloat16 h = *(__hip_bfloat16*)&s;
  return __bfloat162float(h);
}

// async 16B global->LDS (dest = wave-uniform base + lane*16)
__device__ __forceinline__ void g2l16(const short* g, short* l) {
  __builtin_amdgcn_global_load_lds(
      (const __attribute__((address_space(1))) void*)g,
      (__attribute__((address_space(3))) void*)l, 16, 0, 0);
}

// ---------------- prep: cast X + transpose-cast all 4 weights, one launch ----------------
__global__ __launch_bounds__(256) void prep_kernel(const float* __restrict__ X,
                                                   const float* __restrict__ Wq,
                                                   const float* __restrict__ Wk,
                                                   const float* __restrict__ Wv,
                                                   const float* __restrict__ Wo,
                                                   short* __restrict__ Xb,
                                                   short* __restrict__ BtQKV,
                                                   short* __restrict__ Wot) {
  __shared__ float tile[32][33];
  int bid = blockIdx.x;
  if (bid < 4096) {
    int i = bid * 256 + threadIdx.x;
    const float4* p = reinterpret_cast<const float4*>(X) + (size_t)i * 2;
    float4 a = p[0], b = p[1];
    short8 o;
    o[0] = bf16r(a.x); o[1] = bf16r(a.y); o[2] = bf16r(a.z); o[3] = bf16r(a.w);
    o[4] = bf16r(b.x); o[5] = bf16r(b.y); o[6] = bf16r(b.z); o[7] = bf16r(b.w);
    reinterpret_cast<short8*>(Xb)[i] = o;
    return;
  }
  int t = bid - 4096;
  const float* in;
  short* out;
  int N;
  if (t < 1024)      { in = Wq; out = BtQKV;               N = 1024; }
  else if (t < 1536) { t -= 1024; in = Wk; out = BtQKV + 1024 * 1024; N = 512; }
  else if (t < 2048) { t -= 1536; in = Wv; out = BtQKV + 1536 * 1024; N = 512; }
  else               { t -= 2048; in = Wo; out = Wot;                N = 1024; }
  int ntx = N >> 5;
  int n0 = (t % ntx) * 32, k0 = (t / ntx) * 32;
  int tx = threadIdx.x & 31, ty = threadIdx.x >> 5;
  for (int i = 0; i < 32; i += 8)
    tile[ty + i][tx] = in[(size_t)(k0 + ty + i) * N + n0 + tx];
  __syncthreads();
  for (int i = 0; i < 32; i += 8)
    out[(size_t)(n0 + ty + i) * 1024 + k0 + tx] = bf16r(tile[tx][ty + i]);
}

// ---------------- GEMM1 fused, 256x256 tile, BK=64, 8-phase counted-vmcnt schedule ----
// T2 (XOR-swizzled staging, 0-conflict ds_read_b128) + T3/T4 (8-phase, vmcnt(6) only at
// phase 4/8, never 0 in steady state) + T5 (setprio around MFMA cluster) + T1 (bijective
// XCD swizzle: each XCD owns 4 contiguous M-row tiles -> A panel L2-resident).
// Race-freedom ledger (structural, no timing assumptions):
//   group g (4 phases) computes K-tile g from buf[g&1], quadrants (0,0),(0,1),(1,1),(1,0).
//   B(c=0) frags held in regs from ph1 through ph4 (no re-read).
//   stage ph1: tile g+1 A-hi   -> buf[(g+1)&1]  (region last read: group g-1 ph3)
//   stage ph2: tile g+2 A-lo   -> buf[g&1]      (region last read: ph1, before ph1 close barrier)
//   stage ph3: tile g+2 B-hi   -> buf[g&1]      (region last read: ph2)
//   stage ph4: tile g+2 B-lo   -> buf[g&1]      (region last read: ph1)
//   vmcnt(6) at ph4 retires tile g+1 completely before group g+1 reads it.
// K-RoPE stays OUT (R9: transcendentals here cost occupancy); V epilogue = LDS transpose.
__global__ __launch_bounds__(512, 2) void gemm_qkv(const short* __restrict__ A,
                                                   const short* __restrict__ Bt,
                                                   short* __restrict__ Cqkv,
                                                   short* __restrict__ Vt) {
  __shared__ __align__(16) short SH[65536]; // 128 KiB: 2 bufs x (A 16K + B 16K shorts)
  const int tid = threadIdx.x;
  const int wave = tid >> 6, lane = tid & 63;
  const int quad = lane >> 4, l16 = lane & 15;
  const int wr = wave >> 2, wc = wave & 3;
  // bijective XCD swizzle (256 wgs, 8 XCDs, nwg%8==0)
  int fid = blockIdx.y * 8 + blockIdx.x;
  int swz = (fid & 7) * 32 + (fid >> 3);
  const int bx = swz & 7;
  const int m0 = (swz >> 3) << 8, n0 = bx << 8;
  const int nt = 16; // K=1024 / BK=64

  floatx4 acc[2][2][4][2];
#pragma unroll
  for (int r = 0; r < 2; ++r)
#pragma unroll
    for (int c = 0; c < 2; ++c)
#pragma unroll
      for (int mi = 0; mi < 4; ++mi)
#pragma unroll
        for (int ni = 0; ni < 2; ++ni)
          acc[r][c][mi][ni] = (floatx4){0.f, 0.f, 0.f, 0.f};

  const int srow = tid >> 3;                 // 0..63 (row within 64-row stage op)
  const int schunk = (tid & 7) ^ (srow & 7); // pre-swizzled source chunk

// stage one 128x64 half-tile (2 x global_load_lds_dwordx4 per lane-set)
#define STAGE(tile_, src_, row0_, ldso_)                                             \
  do {                                                                               \
    int t_ = (tile_);                                                                \
    if (t_ < nt) {                                                                   \
      short* bb_ = SH + ((t_ & 1) << 15) + (ldso_);                                  \
      const short* sp_ =                                                             \
          (src_) + ((size_t)((row0_) + srow) << 10) + (t_ << 6) + (schunk << 3);     \
      g2l16(sp_, bb_ + (wave << 9));                                                 \
      g2l16(sp_ + (64 << 10), bb_ + 4096 + (wave << 9));                             \
    }                                                                                \
  } while (0)

#define LDA(rhalf_)                                                                  \
  do {                                                                               \
    _Pragma("unroll") for (int mi = 0; mi < 4; ++mi) {                               \
      int R = (rhalf_) * 128 + wr * 64 + mi * 16 + l16;                              \
      _Pragma("unroll") for (int k = 0; k < 2; ++k) {                                \
        int pos = (k * 4 + quad) ^ (R & 7);                                          \
        af[mi][k] = *(const short8*)&Ab[R * 64 + pos * 8];                           \
      }                                                                              \
    }                                                                                \
  } while (0)

#define LDB(dst_, chalf_)                                                            \
  do {                                                                               \
    _Pragma("unroll") for (int ni = 0; ni < 2; ++ni) {                               \
      int R = (chalf_) * 128 + wc * 32 + ni * 16 + l16;                              \
      _Pragma("unroll") for (int k = 0; k < 2; ++k) {                                \
        int pos = (k * 4 + quad) ^ (R & 7);                                          \
        dst_[ni][k] = *(const short8*)&Bb[R * 64 + pos * 8];                         \
      }                                                                              \
    }                                                                                \
  } while (0)

#define MFMA_Q(r_, c_, bf_)                                                          \
  do {                                                                               \
    _Pragma("unroll") for (int mi = 0; mi < 4; ++mi)                                 \
        _Pragma("unroll") for (int ni = 0; ni < 2; ++ni) {                           \
      acc[r_][c_][mi][ni] = __builtin_amdgcn_mfma_f32_16x16x32_bf16(                 \
          af[mi][0], bf_[ni][0], acc[r_][c_][mi][ni], 0, 0, 0);                      \
      acc[r_][c_][mi][ni] = __builtin_amdgcn_mfma_f32_16x16x32_bf16(                 \
          af[mi][1], bf_[ni][1], acc[r_][c_][mi][ni], 0, 0, 0);                      \
    }                                                                                \
  } while (0)

#define PH_OPEN()                                                                    \
  do {                                                                               \
    __builtin_amdgcn_s_barrier();                                                    \
    asm volatile("s_waitcnt lgkmcnt(0)");                                            \
    __builtin_amdgcn_s_setprio(1);                                                   \
  } while (0)
#define PH_CLOSE()                                                                   \
  do {                                                                               \
    __builtin_amdgcn_s_setprio(0);                                                   \
    __builtin_amdgcn_s_barrier();                                                    \
  } while (0)

  // half-tile LDS offsets (shorts): A-lo 0, A-hi 8192, B-lo 16384, B-hi 24576
  // prologue: tile0 all 4 halves + tile1 {A-lo, B-hi, B-lo}; drain to vmcnt(6)
  STAGE(0, A, m0, 0);
  STAGE(0, Bt, n0 + 128, 24576);
  STAGE(0, Bt, n0, 16384);
  STAGE(0, A, m0 + 128, 8192);
  STAGE(1, A, m0, 0);
  STAGE(1, Bt, n0 + 128, 24576);
  STAGE(1, Bt, n0, 16384);
  asm volatile("s_waitcnt vmcnt(6)" ::: "memory");
  __builtin_amdgcn_s_barrier();

  short8 af[4][2], bf0[2][2], bf1[2][2];
  for (int g = 0; g < nt; ++g) {
    const short* Ab = SH + ((g & 1) << 15);
    const short* Bb = Ab + 16384;
    // phase 1: Q(0,0)
    LDA(0);
    LDB(bf0, 0);
    STAGE(g + 1, A, m0 + 128, 8192); // next tile A-hi
    PH_OPEN();
    MFMA_Q(0, 0, bf0);
    PH_CLOSE();
    // phase 2: Q(0,1)
    LDB(bf1, 1);
    STAGE(g + 2, A, m0, 0); // tile+2 A-lo
    PH_OPEN();
    MFMA_Q(0, 1, bf1);
    PH_CLOSE();
    // phase 3: Q(1,1)
    LDA(1);
    STAGE(g + 2, Bt, n0 + 128, 24576); // tile+2 B-hi
    PH_OPEN();
    MFMA_Q(1, 1, bf1);
    PH_CLOSE();
    // phase 4: Q(1,0)  (B c=0 frags reused from registers -- no ds_read)
    STAGE(g + 2, Bt, n0, 16384); // tile+2 B-lo
    PH_OPEN();
    MFMA_Q(1, 0, bf0);
    __builtin_amdgcn_s_setprio(0);
    if (g + 2 < nt)
      asm volatile("s_waitcnt vmcnt(6)" ::: "memory"); // tile g+1 fully landed
    else
      asm volatile("s_waitcnt vmcnt(0)" ::: "memory"); // tail drain
    __builtin_amdgcn_s_barrier();
  }

  if (bx < 6) {
    // ---- Q and K tiles: plain bf16 store (RoPE on K applied by rope_k after) ----
#pragma unroll
    for (int r = 0; r < 2; ++r)
#pragma unroll
      for (int c = 0; c < 2; ++c)
#pragma unroll
        for (int mi = 0; mi < 4; ++mi)
#pragma unroll
          for (int ni = 0; ni < 2; ++ni)
#pragma unroll
            for (int rr = 0; rr < 4; ++rr) {
              int row = m0 + r * 128 + wr * 64 + mi * 16 + quad * 4 + rr;
              int col = n0 + c * 128 + wc * 32 + ni * 16 + l16;
              Cqkv[(size_t)row * 2048 + col] = bf16r(acc[r][c][mi][ni][rr]);
            }
  } else {
    // ---- V tiles: LDS roundtrip transpose -> Vt (B,NKV,D,T), 2 chunks of 128 d ----
    const int b = m0 >> 9, t0 = m0 & (Tn - 1);
#pragma unroll
    for (int ch = 0; ch < 2; ++ch) {
      __syncthreads();
#pragma unroll
      for (int r = 0; r < 2; ++r)
#pragma unroll
        for (int mi = 0; mi < 4; ++mi)
#pragma unroll
          for (int ni = 0; ni < 2; ++ni)
#pragma unroll
            for (int rr = 0; rr < 4; ++rr) {
              int t = r * 128 + wr * 64 + mi * 16 + quad * 4 + rr;
              int d = wc * 32 + ni * 16 + l16;
              SH[d * 264 + t] = bf16r(acc[r][ch][mi][ni][rr]);
            }
      __syncthreads();
      int kv = (bx - 6) * 2 + ch;
#pragma unroll
      for (int u = 0; u < 8; ++u) {
        int idx = tid + u * 512;
        int d = idx >> 5, tb = (idx & 31) << 3;
        short8 vv = *(short8*)&SH[d * 264 + tb];
        *(short8*)&Vt[((size_t)(b * NKVn + kv) * 128 + d) * Tn + t0 + tb] = vv;
      }
    }
  }
#undef STAGE
#undef LDA
#undef LDB
#undef MFMA_Q
#undef PH_OPEN
#undef PH_CLOSE
}

// ---------------- RoPE on K only (cols [1024,1536)), vectorized short8 ----------------
__global__ void rope_k_kernel(short* __restrict__ C) {
  int idx = blockIdx.x * blockDim.x + threadIdx.x; // 262144
  int vec = idx & 7;
  int head = (idx >> 3) & 3;
  int bt = idx >> 5;
  int t = bt & (Tn - 1);
  int i0 = vec * 8;
  size_t base = (size_t)bt * 2048 + 1024 + head * 128 + i0;
  short8 x1 = *(short8*)&C[base];
  short8 x2 = *(short8*)&C[base + 64];
  short8 o1, o2;
  float tf = (float)t;
#pragma unroll
  for (int j = 0; j < 8; ++j) {
    float a = tf * exp2f(-0.2076205059f * (float)(i0 + j)); // log2(10000)/64
    float s, c;
    sincosf(a, &s, &c);
    float v1 = bf16f(x1[j]), v2 = bf16f(x2[j]);
    o1[j] = bf16r(v1 * c - v2 * s);
    o2[j] = bf16r(v2 * c + v1 * s);
  }
  *(short8*)&C[base] = o1;
  *(short8*)&C[base + 64] = o2;
}

// ---------------- GEMM 128x128 (gemm2): C = A(MxK) * Bt(NxK)^T, f32 out ----------------
// NOTE (R6): do NOT narrow the tile; drain-bound, narrower tile = fewer MFMA per drain.
template <bool OUTF32>
__global__ __launch_bounds__(256) void gemm_bt(const short* __restrict__ A,
                                               const short* __restrict__ Bt,
                                               void* __restrict__ Cout,
                                               int M, int N, int K) {
  __shared__ __align__(16) short As[128 * 64];
  __shared__ __align__(16) short Bs[128 * 64];
  const int tid = threadIdx.x;
  const int wave = tid >> 6, lane = tid & 63;
  const int quad = lane >> 4, l16 = lane & 15;
  const int wrow = wave >> 1, wcol = wave & 1;
  const int m0 = blockIdx.y * 128, n0 = blockIdx.x * 128;
  floatx4 acc[4][4];
  for (int mi = 0; mi < 4; ++mi)
    for (int ni = 0; ni < 4; ++ni)
      acc[mi][ni] = (floatx4){0.f, 0.f, 0.f, 0.f};

  for (int kt = 0; kt < K; kt += 64) {
#pragma unroll
    for (int v = 0; v < 4; ++v) {
      int s = tid + v * 256;
      int r = s >> 3;
      int c = (s & 7) ^ (r & 7);
      short* dstA = (short*)As + (size_t)(v * 256 + wave * 64) * 8;
      g2l16(&A[(size_t)(m0 + r) * K + kt + c * 8], dstA);
      short* dstB = (short*)Bs + (size_t)(v * 256 + wave * 64) * 8;
      g2l16(&Bt[(size_t)(n0 + r) * K + kt + c * 8], dstB);
    }
    __syncthreads();
#pragma unroll
    for (int kc = 0; kc < 2; ++kc) {
      short8 af[4], bfr[4];
#pragma unroll
      for (int mi = 0; mi < 4; ++mi) {
        int R = wrow * 64 + mi * 16 + l16;
        int pos = (kc * 4 + quad) ^ (R & 7);
        af[mi] = *(short8*)&As[R * 64 + pos * 8];
      }
#pragma unroll
      for (int ni = 0; ni < 4; ++ni) {
        int R = wcol * 64 + ni * 16 + l16;
        int pos = (kc * 4 + quad) ^ (R & 7);
        bfr[ni] = *(short8*)&Bs[R * 64 + pos * 8];
      }
#pragma unroll
      for (int mi = 0; mi < 4; ++mi)
#pragma unroll
        for (int ni = 0; ni < 4; ++ni)
          acc[mi][ni] = __builtin_amdgcn_mfma_f32_16x16x32_bf16(af[mi], bfr[ni], acc[mi][ni], 0, 0, 0);
    }
    __syncthreads();
  }
#pragma unroll
  for (int mi = 0; mi < 4; ++mi)
#pragma unroll
    for (int ni = 0; ni < 4; ++ni)
#pragma unroll
      for (int r = 0; r < 4; ++r) {
        int row = m0 + wrow * 64 + mi * 16 + quad * 4 + r;
        int col = n0 + wcol * 64 + ni * 16 + l16;
        if (OUTF32)
          ((float*)Cout)[(size_t)row * N + col] = acc[mi][ni][r];
        else
          ((short*)Cout)[(size_t)row * N + col] = bf16r(acc[mi][ni][r]);
      }
}

// ---------------- Flash attention ----------------
// 1024 blocks, qt-major reversed (LPT). 64 q rows/block, 4 waves x 16 rows.
// Fixed-max softmax, scale folded into q-frag, Q-RoPE in-register,
// g2l16 + XOR-swizzled staging (0 conflicts).
__global__ __launch_bounds__(256) void attn_kernel(const short* __restrict__ Cqkv,
                                                   const short* __restrict__ Vt,
                                                   short* __restrict__ Aout) {
  __shared__ __align__(16) short Ks[64 * 128];  // keys x d, chunk pos = c ^ (r&15)
  __shared__ __align__(16) short Vs[128 * 64];  // d x keys, chunk pos = c ^ (r&7)
  __shared__ short Ps[4][16][72];               // per-wave P (C->A layout round trip)
  const int tid = threadIdx.x;
  const int wave = tid >> 6, lane = tid & 63;
  const int quad = lane >> 4, l16 = lane & 15;
  const int blk = blockIdx.x;
  const int qt = 7 - (blk >> 7);    // heavy q-tiles dispatch first
  const int h = blk & 7, b = (blk >> 3) & 15;
  const int kvh = h >> 1;
  const short* Qp = Cqkv + (size_t)b * Tn * 2048 + h * 128;
  const short* Kp = Cqkv + (size_t)b * Tn * 2048 + 1024 + kvh * 128;
  const short* Vtp = Vt + (size_t)(b * NKVn + kvh) * 128 * Tn;

  const int qrow0 = qt * 64 + wave * 16;
  const float scale = 0.08838834764831845f; // 1/sqrt(128)

  short8 qf[4];
#pragma unroll
  for (int kc = 0; kc < 4; ++kc)
    qf[kc] = *(const short8*)&Qp[(size_t)(qrow0 + l16) * 2048 + kc * 32 + quad * 8];
  {
    float tf = (float)(qrow0 + l16);
#pragma unroll
    for (int kc = 0; kc < 2; ++kc)
#pragma unroll
      for (int j = 0; j < 8; ++j) {
        int d = kc * 32 + quad * 8 + j;
        float a = tf * exp2f(-0.2076205059f * (float)d);
        float s, c;
        sincosf(a, &s, &c);
        float x1 = bf16f(qf[kc][j]), x2 = bf16f(qf[kc + 2][j]);
        qf[kc][j] = bf16r((x1 * c - x2 * s) * scale);
        qf[kc + 2][j] = bf16r((x2 * c + x1 * s) * scale);
      }
  }

  floatx4 o[8];
  float l_part[4];
#pragma unroll
  for (int ni = 0; ni < 8; ++ni) o[ni] = (floatx4){0.f, 0.f, 0.f, 0.f};
#pragma unroll
  for (int r = 0; r < 4; ++r) l_part[r] = 0.f;

  const int nk = qt * 64 + 64;

  for (int k0 = 0; k0 < nk; k0 += 64) {
#pragma unroll
    for (int v = 0; v < 4; ++v) {
      int s = tid + v * 256;
      int r = s >> 4, c = (s & 15) ^ (r & 15);
      short* dstK = (short*)Ks + (size_t)(v * 256 + wave * 64) * 8;
      g2l16(&Kp[(size_t)(k0 + r) * 2048 + c * 8], dstK);
    }
#pragma unroll
    for (int v = 0; v < 4; ++v) {
      int s = tid + v * 256;
      int r = s >> 3, c = (s & 7) ^ (r & 7);
      short* dstV = (short*)Vs + (size_t)(v * 256 + wave * 64) * 8;
      g2l16(&Vtp[(size_t)r * Tn + k0 + c * 8], dstV);
    }
    __syncthreads();

    floatx4 s[4];
#pragma unroll
    for (int ni = 0; ni < 4; ++ni) {
      s[ni] = (floatx4){0.f, 0.f, 0.f, 0.f};
      short8 kf[4];
#pragma unroll
      for (int kc = 0; kc < 4; ++kc) {
        int R = ni * 16 + l16;
        int pos = (kc * 4 + quad) ^ (R & 15);
        kf[kc] = *(short8*)&Ks[R * 128 + pos * 8];
      }
#pragma unroll
      for (int kc = 0; kc < 4; ++kc)
        s[ni] = __builtin_amdgcn_mfma_f32_16x16x32_bf16(qf[kc], kf[kc], s[ni], 0, 0, 0);
    }

    const bool diag = (k0 + 63 > qrow0);
#pragma unroll
    for (int ni = 0; ni < 4; ++ni)
#pragma unroll
      for (int r = 0; r < 4; ++r) {
        float p = __expf(s[ni][r]);
        if (diag) {
          int key = k0 + ni * 16 + l16;
          int qr = qrow0 + quad * 4 + r;
          if (key > qr) p = 0.f;
        }
        s[ni][r] = p;
        l_part[r] += p;
      }

#pragma unroll
    for (int ni = 0; ni < 4; ++ni)
#pragma unroll
      for (int r = 0; r < 4; ++r)
        Ps[wave][quad * 4 + r][ni * 16 + l16] = bf16r(s[ni][r]);

    short8 pf[2];
#pragma unroll
    for (int kc = 0; kc < 2; ++kc)
      pf[kc] = *(short8*)&Ps[wave][l16][kc * 32 + quad * 8];
#pragma unroll
    for (int ni = 0; ni < 8; ++ni) {
      int R = ni * 16 + l16;
      int pos0 = quad ^ (R & 7);
      int pos1 = (4 + quad) ^ (R & 7);
      short8 vf0 = *(short8*)&Vs[R * 64 + pos0 * 8];
      short8 vf1 = *(short8*)&Vs[R * 64 + pos1 * 8];
      o[ni] = __builtin_amdgcn_mfma_f32_16x16x32_bf16(pf[0], vf0, o[ni], 0, 0, 0);
      o[ni] = __builtin_amdgcn_mfma_f32_16x16x32_bf16(pf[1], vf1, o[ni], 0, 0, 0);
    }
    __syncthreads();
  }

  float inv[4];
#pragma unroll
  for (int r = 0; r < 4; ++r) {
    float rs = l_part[r];
#pragma unroll
    for (int off = 8; off >= 1; off >>= 1) rs += __shfl_xor(rs, off, 16);
    inv[r] = 1.0f / rs;
  }
#pragma unroll
  for (int ni = 0; ni < 8; ++ni)
#pragma unroll
    for (int r = 0; r < 4; ++r) {
      int t = qrow0 + quad * 4 + r;
      int d = ni * 16 + l16;
      Aout[((size_t)b * Tn + t) * 1024 + h * 128 + d] = bf16r(o[ni][r] * inv[r]);
    }
}

extern "C" void kernel_launch(void* const* d_in, const int* in_sizes, int n_in,
                              void* d_out, int out_size, void* d_ws, size_t ws_size,
                              hipStream_t stream) {
  const float* X  = (const float*)d_in[0];
  const float* Wq = (const float*)d_in[1];
  const float* Wk = (const float*)d_in[2];
  const float* Wv = (const float*)d_in[3];
  const float* Wo = (const float*)d_in[4];

  char* ws = (char*)d_ws;
  short* Xb    = (short*)(ws);                 // 8192x1024 bf16 = 16 MB
  short* BtQKV = (short*)(ws + (16ull << 20)); // 2048x1024 bf16 = 4 MB
  short* Wot   = (short*)(ws + (20ull << 20)); // 1024x1024 bf16 = 2 MB
  short* Cqkv  = (short*)(ws + (22ull << 20)); // 8192x2048 bf16 = 32 MB (V region dead)
  short* Vt    = (short*)(ws + (54ull << 20)); // 16x4x128x512 bf16 = 8 MB
  short* Aout  = (short*)(ws + (62ull << 20)); // 8192x1024 bf16 = 16 MB (end 78 MB)

  prep_kernel<<<7168, 256, 0, stream>>>(X, Wq, Wk, Wv, Wo, Xb, BtQKV, Wot);
  gemm_qkv<<<dim3(8, 32), 512, 0, stream>>>(Xb, BtQKV, Cqkv, Vt);
  rope_k_kernel<<<1024, 256, 0, stream>>>(Cqkv);
  attn_kernel<<<1024, 256, 0, stream>>>(Cqkv, Vt, Aout);
  gemm_bt<true><<<dim3(8, 64), 256, 0, stream>>>(Aout, Wot, d_out, 8192, 1024, 1024);
}